// Round 3
// baseline (787.296 us; speedup 1.0000x reference)
//
#include <hip/hip_runtime.h>
#include <math.h>

// Problem constants (from reference: z (32,4096,256) f32, embed (1024,256) f32)
#define N_TOK   131072
#define DIM     256
#define K_CODE  1024
#define KEXT    768       // extended K: [zh,zh,zl] x [ch,cl,ch], c pre-normalized
#define MARGIN  2e-3f     // top1-top2 gap below which we redo in fp64
                          // worst-case residual (zl.cl + fp32 accum) ~<1.6e-3; passed at 0 absmax

// Workspace layout (bytes)
#define WS_COUNTS   0         // 1024 * int      (histogram)
#define WS_LOSS     4096      // double          (sum of squared diffs)
#define WS_RCOUNT   4104      // int             (recheck-list count)
#define WS_DONE     4112      // int             (output-blocks-done counter)
#define WS_FIDX     16384     // N_TOK * int     (final argmax index per token)
#define WS_RLIST    1048576   // N_TOK * int     (tokens needing fp64 recheck)
#define WS_BEXT     2097152   // 1024*768 bf16 = 1.5 MB packed normalized codebook

#define CHUNK_BYTES 49152     // 32 codes x 768 x 2B, one LDS buffer

// Output layout (floats): z_q_st[33554432], loss, perplexity, indices[131072]
#define OUT_LOSS  33554432
#define OUT_PERP  33554433
#define OUT_IDX   33554434

typedef __bf16 bf16x8 __attribute__((ext_vector_type(8)));
typedef float  f32x4  __attribute__((ext_vector_type(4)));

// round-to-nearest-even fp32 -> bf16 bits
static __device__ __forceinline__ unsigned short f2bf(float f) {
    unsigned int u = __float_as_uint(f);
    u += 0x7FFFu + ((u >> 16) & 1u);
    return (unsigned short)(u >> 16);
}
static __device__ __forceinline__ float bf2f(unsigned short h) {
    return __uint_as_float(((unsigned int)h) << 16);
}

// async global->LDS, 16B per lane; LDS dest = wave-uniform base + lane*16
static __device__ __forceinline__ void load_lds16(const void* g, void* l) {
    __builtin_amdgcn_global_load_lds(
        (const __attribute__((address_space(1))) unsigned int*)g,
        (__attribute__((address_space(3))) unsigned int*)l, 16, 0, 0);
}

// ---------------------------------------------------------------- Phase A ---
// Fused: normalize codebook rows + pack B_ext image + zero ws header.
// One wave per code (4 codes/block, 256 blocks). Per code k, K-dim kk in
// [0,768): kk<256 -> bf16hi(chat[kk]), kk<512 -> bf16lo(chat[kk-256]),
// else bf16hi(chat[kk-512]), where chat = c / max(||c||,eps). Layout is the
// exact per-chunk LDS image: chunk c (32 codes) is 48 KB of
// [nt(2)][ks24(24)][quad(4)][col(16)][j(8)] bf16, so global_load_lds can
// stage it as 1 KB contiguous segments and ds_read_b128 at lane*16 yields
// the MFMA B-fragment (B[n=lane&15][k=quad*8+j]) directly.
__global__ void vq_pack(const float* __restrict__ embed, unsigned short* __restrict__ bext,
                        int* __restrict__ wshdr) {
    __shared__ float cs[4][DIM];
    const int tid  = threadIdx.x;
    const int w    = tid >> 6;
    const int lane = tid & 63;
    const int k0   = blockIdx.x * 4;

    // block 0 zeroes the 16 KB ws header (counts, loss, rcount, done)
    if (blockIdx.x == 0) {
        for (int i = tid; i < 4096; i += 256) wshdr[i] = 0;
    }

    // wave w normalizes code k0+w into LDS
    {
        const int k = k0 + w;
        float4 v = *(const float4*)&embed[k * DIM + lane * 4];
        float s = v.x * v.x + v.y * v.y + v.z * v.z + v.w * v.w;
        #pragma unroll
        for (int off = 32; off; off >>= 1) s += __shfl_xor(s, off);
        float inv = 1.0f / fmaxf(sqrtf(s), 1e-12f);
        float4 nv;
        nv.x = v.x * inv; nv.y = v.y * inv; nv.z = v.z * inv; nv.w = v.w * inv;
        *(float4*)&cs[w][lane * 4] = nv;
    }
    __syncthreads();

    // emit 4 codes x 96 ushort8 groups = 384 16B stores
    for (int t = tid; t < 384; t += 256) {
        int lc  = t / 96;          // local code
        int g   = t - lc * 96;     // group
        int k   = k0 + lc;
        int kk0 = g * 8;
        int src, hi;
        if (kk0 < 256)      { src = kk0;       hi = 1; }
        else if (kk0 < 512) { src = kk0 - 256; hi = 0; }
        else                { src = kk0 - 512; hi = 1; }
        unsigned short r[8] __attribute__((aligned(16)));
        #pragma unroll
        for (int j = 0; j < 8; ++j) {
            float vv = cs[lc][src + j];
            unsigned short h = f2bf(vv);
            r[j] = hi ? h : f2bf(vv - bf2f(h));
        }
        int c = k >> 5, kin = k & 31;
        int nt = kin >> 4, col = kin & 15;
        int ks = kk0 >> 5, quad = (kk0 >> 3) & 3;
        size_t dst = (size_t)c * CHUNK_BYTES + (size_t)(((nt * 24 + ks) * 64) + quad * 16 + col) * 16;
        *(float4*)((char*)bext + dst) = *(const float4*)r;
    }
}

// ---------------------------------------------------------------- Phase B ---
// MFMA argmax GEMM, K=768 ([zh,zh,zl] . [ch,cl,ch], codebook pre-normalized).
// Block: 128 tokens (4 waves x 2 m-tiles), all 1024 codes in 32 chunks of 32.
// A fragments live in registers (128 VGPRs, loaded once); B chunk staged to
// LDS (48 KB) via global_load_lds; each B fragment (ds_read_b128) feeds 2
// MFMAs. 2 barriers and 96 MFMAs/wave per chunk. Independent 4-wave blocks
// (2-3 resident/CU) desynchronize naturally -> MFMA/LDS/VALU phases of
// different blocks overlap (m114). Top-2 tracked; gap < MARGIN -> exact
// fp64 re-resolution later. Scores are z.chat directly (no epilogue scale).
__launch_bounds__(256, 2)
__global__ void vq_argmax(const float* __restrict__ z,
                          const unsigned short* __restrict__ bext,
                          int* __restrict__ fidx,
                          int* __restrict__ rcount, int* __restrict__ rlist) {
    __shared__ unsigned short bbuf[CHUNK_BYTES / 2];   // 48 KB

    const int tid  = threadIdx.x;
    const int w    = tid >> 6;
    const int lane = tid & 63;
    const int col  = lane & 15;
    const int quad = lane >> 4;
    const int tokBase = blockIdx.x * 128;

    // ---- A fragments: wave w owns tokens [w*32, w*32+32). Per m-tile (16
    // rows): zh/zl frags for 8 k-steps of 32. A[m=lane&15][k=quad*8+j].
    bf16x8 ah[2][8], al[2][8];
    #pragma unroll
    for (int mt = 0; mt < 2; ++mt) {
        const float* zr = z + (size_t)(tokBase + w * 32 + mt * 16 + col) * DIM;
        #pragma unroll
        for (int ks = 0; ks < 8; ++ks) {
            float4 f0 = *(const float4*)(zr + ks * 32 + quad * 8);
            float4 f1 = *(const float4*)(zr + ks * 32 + quad * 8 + 4);
            float v[8] = {f0.x, f0.y, f0.z, f0.w, f1.x, f1.y, f1.z, f1.w};
            union { bf16x8 v; unsigned short u[8]; } th, tl;
            #pragma unroll
            for (int j = 0; j < 8; ++j) {
                unsigned short h = f2bf(v[j]);
                th.u[j] = h;
                tl.u[j] = f2bf(v[j] - bf2f(h));
            }
            ah[mt][ks] = th.v;
            al[mt][ks] = tl.v;
        }
    }

    float best[2][4], second[2][4];
    int   bidx[2][4];
    #pragma unroll
    for (int mt = 0; mt < 2; ++mt)
        #pragma unroll
        for (int r = 0; r < 4; ++r) { best[mt][r] = -1e30f; second[mt][r] = -1e30f; bidx[mt][r] = 0; }

    for (int c = 0; c < 32; ++c) {
        __syncthreads();   // previous chunk's readers done
        {   // stage 48 KB: wave w stages segments [w*12, w*12+12)
            const char* gsrc = (const char*)bext + (size_t)c * CHUNK_BYTES;
            #pragma unroll
            for (int i = 0; i < 12; ++i) {
                int seg = w * 12 + i;
                load_lds16(gsrc + (size_t)seg * 1024 + lane * 16,
                           (char*)bbuf + seg * 1024);
            }
        }
        __syncthreads();   // drains vmcnt (global_load_lds) via barrier semantics

        f32x4 acc[2][2];
        #pragma unroll
        for (int mt = 0; mt < 2; ++mt)
            #pragma unroll
            for (int nt = 0; nt < 2; ++nt) acc[mt][nt] = (f32x4){0.f, 0.f, 0.f, 0.f};

        #pragma unroll
        for (int nt = 0; nt < 2; ++nt) {
            const unsigned short* bb = bbuf + nt * 24 * 512;   // ushort index
            #pragma unroll
            for (int ks = 0; ks < 8; ++ks) {   // zh . ch
                bf16x8 b = *(const bf16x8*)&bb[ks * 512 + lane * 8];
                acc[0][nt] = __builtin_amdgcn_mfma_f32_16x16x32_bf16(ah[0][ks], b, acc[0][nt], 0, 0, 0);
                acc[1][nt] = __builtin_amdgcn_mfma_f32_16x16x32_bf16(ah[1][ks], b, acc[1][nt], 0, 0, 0);
            }
            #pragma unroll
            for (int ks = 0; ks < 8; ++ks) {   // zh . cl
                bf16x8 b = *(const bf16x8*)&bb[(8 + ks) * 512 + lane * 8];
                acc[0][nt] = __builtin_amdgcn_mfma_f32_16x16x32_bf16(ah[0][ks], b, acc[0][nt], 0, 0, 0);
                acc[1][nt] = __builtin_amdgcn_mfma_f32_16x16x32_bf16(ah[1][ks], b, acc[1][nt], 0, 0, 0);
            }
            #pragma unroll
            for (int ks = 0; ks < 8; ++ks) {   // zl . ch
                bf16x8 b = *(const bf16x8*)&bb[(16 + ks) * 512 + lane * 8];
                acc[0][nt] = __builtin_amdgcn_mfma_f32_16x16x32_bf16(al[0][ks], b, acc[0][nt], 0, 0, 0);
                acc[1][nt] = __builtin_amdgcn_mfma_f32_16x16x32_bf16(al[1][ks], b, acc[1][nt], 0, 0, 0);
            }
        }

        // epilogue: per-thread top-2 (scores already ||c||-normalized).
        // Codes ascend for fixed col, so strict > keeps first occurrence;
        // exact tie -> gap 0 -> recheck.
        #pragma unroll
        for (int nt = 0; nt < 2; ++nt) {
            int code = c * 32 + nt * 16 + col;
            #pragma unroll
            for (int mt = 0; mt < 2; ++mt)
                #pragma unroll
                for (int r = 0; r < 4; ++r) {
                    float v = acc[mt][nt][r];
                    if (v > best[mt][r]) { second[mt][r] = best[mt][r]; best[mt][r] = v; bidx[mt][r] = code; }
                    else                 { second[mt][r] = fmaxf(second[mt][r], v); }
                }
        }
    }

    // Merge top-2 across the 16 D-columns (disjoint code sets per lane).
    #pragma unroll
    for (int mt = 0; mt < 2; ++mt)
        #pragma unroll
        for (int r = 0; r < 4; ++r) {
            float B = best[mt][r], S = second[mt][r];
            int   I = bidx[mt][r];
            #pragma unroll
            for (int off = 1; off < 16; off <<= 1) {
                float ob = __shfl_xor(B, off);
                float os = __shfl_xor(S, off);
                int   oi = __shfl_xor(I, off);
                if (ob > B) {
                    S = fmaxf(B, os);
                    B = ob; I = oi;
                } else {
                    if (ob == B && oi < I) I = oi;   // tie: first occurrence
                    S = fmaxf(S, ob);                // ob==B -> gap 0 -> recheck
                }
            }
            if (col == 0) {
                int token = tokBase + w * 32 + mt * 16 + quad * 4 + r;   // D row = quad*4+reg
                fidx[token] = I;
                if (B - S < MARGIN) {
                    int p = atomicAdd(rcount, 1);
                    rlist[p] = token;
                }
            }
        }
}

// ---------------------------------------------------------------- Phase R ---
// Exact fp64 argmax for flagged tokens (full scan of all 1024 codes).
__global__ void vq_recheck(const float* __restrict__ z, const float* __restrict__ embed,
                           const int* __restrict__ rcount, const int* __restrict__ rlist,
                           int* __restrict__ fidx) {
    __shared__ double zd[DIM];
    __shared__ double rv[256];
    __shared__ int    rix[256];
    const int cnt = *rcount;
    for (int li = blockIdx.x; li < cnt; li += gridDim.x) {
        int token = rlist[li];
        __syncthreads();
        zd[threadIdx.x] = (double)z[token * DIM + threadIdx.x];
        __syncthreads();
        double bv = -1e300;
        int    bi = 0;
        #pragma unroll
        for (int j = 0; j < 4; ++j) {
            int k = threadIdx.x * 4 + j;   // ascending per thread
            const float* e = &embed[k * DIM];
            double acc = 0.0, nrm = 0.0;
            for (int d = 0; d < DIM; d += 4) {
                float4 ef = *(const float4*)&e[d];
                acc += (double)ef.x * zd[d]     + (double)ef.y * zd[d + 1] +
                       (double)ef.z * zd[d + 2] + (double)ef.w * zd[d + 3];
                nrm += (double)ef.x * ef.x + (double)ef.y * ef.y +
                       (double)ef.z * ef.z + (double)ef.w * ef.w;
            }
            double val = acc / fmax(sqrt(nrm), 1e-12);   // 1/||z|| scale dropped
            if (val > bv) { bv = val; bi = k; }
        }
        rv[threadIdx.x]  = bv;
        rix[threadIdx.x] = bi;
        __syncthreads();
        for (int s = 128; s; s >>= 1) {
            if (threadIdx.x < s) {
                double v2 = rv[threadIdx.x + s];
                int    i2 = rix[threadIdx.x + s];
                if (v2 > rv[threadIdx.x] ||
                    (v2 == rv[threadIdx.x] && i2 < rix[threadIdx.x])) {
                    rv[threadIdx.x] = v2;
                    rix[threadIdx.x] = i2;
                }
            }
            __syncthreads();
        }
        if (threadIdx.x == 0) fidx[token] = rix[0];
    }
}

// ---------------------------------------------------------------- Phase C ---
// Fused: gather z_q, write z_q_st = z + (z_q - z), accumulate loss in double,
// histogram counts, write index floats; LAST block (done-counter) computes
// perplexity + loss scalars (release/acquire via threadfence + atomic).
__global__ void vq_output(const float* __restrict__ z, const float* __restrict__ embed,
                          const int* __restrict__ fidx, float* __restrict__ out,
                          int* __restrict__ counts, double* __restrict__ lossAcc,
                          int* __restrict__ done) {
    __shared__ double sh[256];
    __shared__ int lastFlag;
    int lane = threadIdx.x & 63;
    int gw   = (blockIdx.x * blockDim.x + threadIdx.x) >> 6;
    int nwav = (gridDim.x * blockDim.x) >> 6;
    double lsum = 0.0;
    for (int t = gw; t < N_TOK; t += nwav) {
        int idx = fidx[t];
        float4 e  = *(const float4*)&embed[idx * DIM + lane * 4];
        float4 zz = *(const float4*)&z[(size_t)t * DIM + lane * 4];
        float4 r, o;
        r.x = e.x - zz.x; r.y = e.y - zz.y; r.z = e.z - zz.z; r.w = e.w - zz.w;
        o.x = zz.x + r.x; o.y = zz.y + r.y; o.z = zz.z + r.z; o.w = zz.w + r.w;
        *(float4*)&out[(size_t)t * DIM + lane * 4] = o;
        lsum += (double)r.x * r.x + (double)r.y * r.y +
                (double)r.z * r.z + (double)r.w * r.w;
        if (lane == 0) {
            atomicAdd(&counts[idx], 1);
            out[OUT_IDX + t] = (float)idx;
        }
    }
    #pragma unroll
    for (int off = 32; off; off >>= 1) lsum += __shfl_down(lsum, off);
    if (lane == 0) atomicAdd(lossAcc, lsum);

    // last-done block finalizes
    __threadfence();           // release: each thread's atomics visible
    __syncthreads();
    if (threadIdx.x == 0) {
        int p = atomicAdd(done, 1);
        lastFlag = (p == (int)gridDim.x - 1);
    }
    __syncthreads();
    if (lastFlag) {
        __threadfence();       // acquire
        double s = 0.0;
        for (int b = threadIdx.x; b < K_CODE; b += 256) {
            double p = (double)counts[b] / (double)N_TOK;
            s += p * log(p + 1e-10);   // p==0 contributes exactly 0
        }
        sh[threadIdx.x] = s;
        __syncthreads();
        for (int st = 128; st; st >>= 1) {
            if (threadIdx.x < st) sh[threadIdx.x] += sh[threadIdx.x + st];
            __syncthreads();
        }
        if (threadIdx.x == 0) {
            out[OUT_PERP] = (float)exp(-sh[0]);
            out[OUT_LOSS] = (float)(1.25 * (*lossAcc) / (double)(N_TOK) / (double)(DIM));
        }
    }
}

// ----------------------------------------------------------------- launch ---
extern "C" void kernel_launch(void* const* d_in, const int* in_sizes, int n_in,
                              void* d_out, int out_size, void* d_ws, size_t ws_size,
                              hipStream_t stream) {
    const float* z     = (const float*)d_in[0];
    const float* embed = (const float*)d_in[1];
    float* out = (float*)d_out;
    char*  ws  = (char*)d_ws;

    int*            counts  = (int*)   (ws + WS_COUNTS);
    double*         lossAcc = (double*)(ws + WS_LOSS);
    int*            rcount  = (int*)   (ws + WS_RCOUNT);
    int*            done    = (int*)   (ws + WS_DONE);
    int*            fidx    = (int*)   (ws + WS_FIDX);
    int*            rlist   = (int*)   (ws + WS_RLIST);
    unsigned short* bext    = (unsigned short*)(ws + WS_BEXT);

    vq_pack   <<<256,  256, 0, stream>>>(embed, bext, (int*)ws);
    vq_argmax <<<N_TOK / 128, 256, 0, stream>>>(z, bext, fidx, rcount, rlist);
    vq_recheck<<<512,  256, 0, stream>>>(z, embed, rcount, rlist, fidx);
    vq_output <<<2048, 256, 0, stream>>>(z, embed, fidx, out, counts, lossAcc, done);
}

// Round 4
// 540.701 us; speedup vs baseline: 1.4561x; 1.4561x over previous
//
#include <hip/hip_runtime.h>
#include <math.h>

// Problem constants (from reference: z (32,4096,256) f32, embed (1024,256) f32)
#define N_TOK   131072
#define DIM     256
#define K_CODE  1024
#define KEXT    768       // extended K: [zh,zh,zl] x [ch,cl,ch], c pre-normalized
#define MARGIN  2e-3f     // top1-top2 gap below which we redo in fp64

// Workspace layout (bytes)
#define WS_COUNTS   0         // 1024 * int      (histogram)
#define WS_LOSSFIX  4096      // double          (recheck loss correction)
#define WS_RCOUNT   4104      // int             (recheck-list count)
#define WS_PART     8192      // 1024 * double   (per-block loss partials)
#define WS_FIDX     16384     // N_TOK * int     (argmax index per token)
#define WS_RLIST    1048576   // N_TOK * int     (tokens needing fp64 recheck)
#define WS_BEXT     2097152   // 1024*768 bf16 = 1.5 MB packed normalized codebook

#define CHUNK_BYTES 49152     // 32 codes x 768 x 2B, one LDS buffer

// Output layout (floats): z_q_st[33554432], loss, perplexity, indices[131072]
#define OUT_LOSS  33554432
#define OUT_PERP  33554433
#define OUT_IDX   33554434

typedef __bf16 bf16x8 __attribute__((ext_vector_type(8)));
typedef float  f32x4  __attribute__((ext_vector_type(4)));

// round-to-nearest-even fp32 -> bf16 bits
static __device__ __forceinline__ unsigned short f2bf(float f) {
    unsigned int u = __float_as_uint(f);
    u += 0x7FFFu + ((u >> 16) & 1u);
    return (unsigned short)(u >> 16);
}
static __device__ __forceinline__ float bf2f(unsigned short h) {
    return __uint_as_float(((unsigned int)h) << 16);
}

// async global->LDS, 16B per lane; LDS dest = wave-uniform base + lane*16
static __device__ __forceinline__ void load_lds16(const void* g, void* l) {
    __builtin_amdgcn_global_load_lds(
        (const __attribute__((address_space(1))) unsigned int*)g,
        (__attribute__((address_space(3))) unsigned int*)l, 16, 0, 0);
}

// ---------------------------------------------------------------- Phase A ---
// Fused: normalize codebook rows + pack B_ext image + zero ws header.
// One wave per code (4 codes/block, 256 blocks). chat = c / max(||c||,eps).
// Layout: chunk c (32 codes) = 48 KB of [nt(2)][ks24(24)][quad(4)][col(16)][j(8)]
// bf16 so global_load_lds stages 1 KB contiguous segments and ds_read_b128 at
// lane*16 yields the MFMA B-fragment (B[n=lane&15][k=quad*8+j]) directly.
__global__ void vq_pack(const float* __restrict__ embed, unsigned short* __restrict__ bext,
                        int* __restrict__ wshdr) {
    __shared__ float cs[4][DIM];
    const int tid  = threadIdx.x;
    const int w    = tid >> 6;
    const int lane = tid & 63;
    const int k0   = blockIdx.x * 4;

    // block 0 zeroes the 16 KB ws header (counts, lossFix, rcount, partials)
    if (blockIdx.x == 0) {
        for (int i = tid; i < 4096; i += 256) wshdr[i] = 0;
    }

    // wave w normalizes code k0+w into LDS
    {
        const int k = k0 + w;
        float4 v = *(const float4*)&embed[k * DIM + lane * 4];
        float s = v.x * v.x + v.y * v.y + v.z * v.z + v.w * v.w;
        #pragma unroll
        for (int off = 32; off; off >>= 1) s += __shfl_xor(s, off);
        float inv = 1.0f / fmaxf(sqrtf(s), 1e-12f);
        float4 nv;
        nv.x = v.x * inv; nv.y = v.y * inv; nv.z = v.z * inv; nv.w = v.w * inv;
        *(float4*)&cs[w][lane * 4] = nv;
    }
    __syncthreads();

    // emit 4 codes x 96 ushort8 groups = 384 16B stores
    for (int t = tid; t < 384; t += 256) {
        int lc  = t / 96;          // local code
        int g   = t - lc * 96;     // group
        int k   = k0 + lc;
        int kk0 = g * 8;
        int src, hi;
        if (kk0 < 256)      { src = kk0;       hi = 1; }
        else if (kk0 < 512) { src = kk0 - 256; hi = 0; }
        else                { src = kk0 - 512; hi = 1; }
        unsigned short r[8] __attribute__((aligned(16)));
        #pragma unroll
        for (int j = 0; j < 8; ++j) {
            float vv = cs[lc][src + j];
            unsigned short h = f2bf(vv);
            r[j] = hi ? h : f2bf(vv - bf2f(h));
        }
        int c = k >> 5, kin = k & 31;
        int nt = kin >> 4, col = kin & 15;
        int ks = kk0 >> 5, quad = (kk0 >> 3) & 3;
        size_t dst = (size_t)c * CHUNK_BYTES + (size_t)(((nt * 24 + ks) * 64) + quad * 16 + col) * 16;
        *(float4*)((char*)bext + dst) = *(const float4*)r;
    }
}

// ---------------------------------------------------------------- Phase B ---
// MFMA argmax GEMM, K=768 ([zh,zh,zl] . [ch,cl,ch], codebook pre-normalized)
// WITH FUSED OUTPUT. Block: 128 tokens (4 waves x 2 m-tiles), 32 chunks of 32
// codes staged via global_load_lds. After the top-2 merge, the wave already
// holds final indices for its 32 tokens -> epilogue broadcasts them via
// __shfl (static reg indices), gathers embed rows (L2), reloads z fp32 (L3:
// z=134MB < 256MB L3), writes z_q_st + index floats + counts, accumulates
// loss per-block (non-atomic partials -> no same-address atomic serializer).
// The ~270MB of output traffic overlaps with other blocks' MFMA (m114).
__launch_bounds__(256, 2)
__global__ void vq_argmax(const float* __restrict__ z,
                          const unsigned short* __restrict__ bext,
                          const float* __restrict__ embed,
                          int* __restrict__ fidx,
                          int* __restrict__ rcount, int* __restrict__ rlist,
                          float* __restrict__ out, int* __restrict__ counts,
                          double* __restrict__ partials) {
    __shared__ unsigned short bbuf[CHUNK_BYTES / 2];   // 48 KB
    __shared__ double shl[4];

    const int tid  = threadIdx.x;
    const int w    = tid >> 6;
    const int lane = tid & 63;
    const int col  = lane & 15;
    const int quad = lane >> 4;
    const int tokBase = blockIdx.x * 128;

    // ---- A fragments: wave w owns tokens [w*32, w*32+32). Per m-tile (16
    // rows): zh/zl frags for 8 k-steps of 32. A[m=lane&15][k=quad*8+j].
    bf16x8 ah[2][8], al[2][8];
    #pragma unroll
    for (int mt = 0; mt < 2; ++mt) {
        const float* zr = z + (size_t)(tokBase + w * 32 + mt * 16 + col) * DIM;
        #pragma unroll
        for (int ks = 0; ks < 8; ++ks) {
            float4 f0 = *(const float4*)(zr + ks * 32 + quad * 8);
            float4 f1 = *(const float4*)(zr + ks * 32 + quad * 8 + 4);
            float v[8] = {f0.x, f0.y, f0.z, f0.w, f1.x, f1.y, f1.z, f1.w};
            union { bf16x8 v; unsigned short u[8]; } th, tl;
            #pragma unroll
            for (int j = 0; j < 8; ++j) {
                unsigned short h = f2bf(v[j]);
                th.u[j] = h;
                tl.u[j] = f2bf(v[j] - bf2f(h));
            }
            ah[mt][ks] = th.v;
            al[mt][ks] = tl.v;
        }
    }

    float best[2][4], second[2][4];
    int   bidx[2][4];
    #pragma unroll
    for (int mt = 0; mt < 2; ++mt)
        #pragma unroll
        for (int r = 0; r < 4; ++r) { best[mt][r] = -1e30f; second[mt][r] = -1e30f; bidx[mt][r] = 0; }

    for (int c = 0; c < 32; ++c) {
        __syncthreads();   // previous chunk's readers done
        {   // stage 48 KB: wave w stages segments [w*12, w*12+12)
            const char* gsrc = (const char*)bext + (size_t)c * CHUNK_BYTES;
            #pragma unroll
            for (int i = 0; i < 12; ++i) {
                int seg = w * 12 + i;
                load_lds16(gsrc + (size_t)seg * 1024 + lane * 16,
                           (char*)bbuf + seg * 1024);
            }
        }
        __syncthreads();   // drains vmcnt (global_load_lds) via barrier semantics

        f32x4 acc[2][2];
        #pragma unroll
        for (int mt = 0; mt < 2; ++mt)
            #pragma unroll
            for (int nt = 0; nt < 2; ++nt) acc[mt][nt] = (f32x4){0.f, 0.f, 0.f, 0.f};

        #pragma unroll
        for (int nt = 0; nt < 2; ++nt) {
            const unsigned short* bb = bbuf + nt * 24 * 512;   // ushort index
            #pragma unroll
            for (int ks = 0; ks < 8; ++ks) {   // zh . ch
                bf16x8 b = *(const bf16x8*)&bb[ks * 512 + lane * 8];
                acc[0][nt] = __builtin_amdgcn_mfma_f32_16x16x32_bf16(ah[0][ks], b, acc[0][nt], 0, 0, 0);
                acc[1][nt] = __builtin_amdgcn_mfma_f32_16x16x32_bf16(ah[1][ks], b, acc[1][nt], 0, 0, 0);
            }
            #pragma unroll
            for (int ks = 0; ks < 8; ++ks) {   // zh . cl
                bf16x8 b = *(const bf16x8*)&bb[(8 + ks) * 512 + lane * 8];
                acc[0][nt] = __builtin_amdgcn_mfma_f32_16x16x32_bf16(ah[0][ks], b, acc[0][nt], 0, 0, 0);
                acc[1][nt] = __builtin_amdgcn_mfma_f32_16x16x32_bf16(ah[1][ks], b, acc[1][nt], 0, 0, 0);
            }
            #pragma unroll
            for (int ks = 0; ks < 8; ++ks) {   // zl . ch
                bf16x8 b = *(const bf16x8*)&bb[(16 + ks) * 512 + lane * 8];
                acc[0][nt] = __builtin_amdgcn_mfma_f32_16x16x32_bf16(al[0][ks], b, acc[0][nt], 0, 0, 0);
                acc[1][nt] = __builtin_amdgcn_mfma_f32_16x16x32_bf16(al[1][ks], b, acc[1][nt], 0, 0, 0);
            }
        }

        // epilogue: per-thread top-2 (scores already ||c||-normalized).
        #pragma unroll
        for (int nt = 0; nt < 2; ++nt) {
            int code = c * 32 + nt * 16 + col;
            #pragma unroll
            for (int mt = 0; mt < 2; ++mt)
                #pragma unroll
                for (int r = 0; r < 4; ++r) {
                    float v = acc[mt][nt][r];
                    if (v > best[mt][r]) { second[mt][r] = best[mt][r]; best[mt][r] = v; bidx[mt][r] = code; }
                    else                 { second[mt][r] = fmaxf(second[mt][r], v); }
                }
        }
    }

    // Merge top-2 across the 16 D-columns (disjoint code sets per lane).
    // After the butterfly, every lane in a quad-group holds the merged result
    // for its quad's rows -> bidx[mt][r] becomes the final index (per quad).
    #pragma unroll
    for (int mt = 0; mt < 2; ++mt)
        #pragma unroll
        for (int r = 0; r < 4; ++r) {
            float B = best[mt][r], S = second[mt][r];
            int   I = bidx[mt][r];
            #pragma unroll
            for (int off = 1; off < 16; off <<= 1) {
                float ob = __shfl_xor(B, off);
                float os = __shfl_xor(S, off);
                int   oi = __shfl_xor(I, off);
                if (ob > B) {
                    S = fmaxf(B, os);
                    B = ob; I = oi;
                } else {
                    if (ob == B && oi < I) I = oi;   // tie: first occurrence
                    S = fmaxf(S, ob);                // ob==B -> gap 0 -> recheck
                }
            }
            bidx[mt][r] = I;   // keep merged index for the gather loop
            if (col == 0) {
                int token = tokBase + w * 32 + mt * 16 + quad * 4 + r;   // D row = quad*4+reg
                fidx[token] = I;
                out[OUT_IDX + token] = (float)I;
                atomicAdd(&counts[I], 1);
                if (B - S < MARGIN) {
                    int p = atomicAdd(rcount, 1);
                    rlist[p] = token;
                }
            }
        }

    // ---- fused output: 32 rows per wave. idx for token (mt,q,r) lives in
    // bidx[mt][r] of any lane with quad==q -> __shfl from lane q*16 (static
    // register indices, runtime src lane -> no scratch).
    double lsum = 0.0;
    #pragma unroll
    for (int mt = 0; mt < 2; ++mt)
        #pragma unroll
        for (int r = 0; r < 4; ++r)
            #pragma unroll
            for (int q = 0; q < 4; ++q) {
                int idxv  = __shfl(bidx[mt][r], q * 16);
                int token = tokBase + w * 32 + mt * 16 + q * 4 + r;
                float4 e  = *(const float4*)&embed[(size_t)idxv * DIM + lane * 4];
                float4 zz = *(const float4*)&z[(size_t)token * DIM + lane * 4];
                float4 rr, o;
                rr.x = e.x - zz.x; rr.y = e.y - zz.y; rr.z = e.z - zz.z; rr.w = e.w - zz.w;
                o.x = zz.x + rr.x; o.y = zz.y + rr.y; o.z = zz.z + rr.z; o.w = zz.w + rr.w;
                *(float4*)&out[(size_t)token * DIM + lane * 4] = o;
                lsum += (double)rr.x * rr.x + (double)rr.y * rr.y +
                        (double)rr.z * rr.z + (double)rr.w * rr.w;
            }

    // wave reduce -> block partial (non-atomic; no same-address serializer)
    #pragma unroll
    for (int off = 32; off; off >>= 1) lsum += __shfl_down(lsum, off);
    if (lane == 0) shl[w] = lsum;
    __syncthreads();
    if (tid == 0) partials[blockIdx.x] = shl[0] + shl[1] + shl[2] + shl[3];
}

// ---------------------------------------------------------------- Phase R ---
// Exact fp64 argmax for flagged tokens + FIXUP: if the exact index differs
// from argmax's, rewrite the out row / index float, adjust counts, and apply
// an exact double loss correction ((double)(f32 residual)^2 terms are exact,
// so subtract-old + add-new reproduces the pure sum).
__global__ void vq_recheck(const float* __restrict__ z, const float* __restrict__ embed,
                           const int* __restrict__ rcount, const int* __restrict__ rlist,
                           int* __restrict__ fidx, float* __restrict__ out,
                           int* __restrict__ counts, double* __restrict__ lossFix) {
    __shared__ double zd[DIM];
    __shared__ double rv[256];
    __shared__ int    rix[256];
    __shared__ int    s_old, s_new;
    const int cnt = *rcount;
    for (int li = blockIdx.x; li < cnt; li += gridDim.x) {
        int token = rlist[li];
        __syncthreads();
        zd[threadIdx.x] = (double)z[(size_t)token * DIM + threadIdx.x];
        if (threadIdx.x == 0) s_old = fidx[token];
        __syncthreads();
        double bv = -1e300;
        int    bi = 0;
        #pragma unroll
        for (int j = 0; j < 4; ++j) {
            int k = threadIdx.x * 4 + j;   // ascending per thread
            const float* e = &embed[k * DIM];
            double acc = 0.0, nrm = 0.0;
            for (int d = 0; d < DIM; d += 4) {
                float4 ef = *(const float4*)&e[d];
                acc += (double)ef.x * zd[d]     + (double)ef.y * zd[d + 1] +
                       (double)ef.z * zd[d + 2] + (double)ef.w * zd[d + 3];
                nrm += (double)ef.x * ef.x + (double)ef.y * ef.y +
                       (double)ef.z * ef.z + (double)ef.w * ef.w;
            }
            double val = acc / fmax(sqrt(nrm), 1e-12);   // 1/||z|| scale dropped
            if (val > bv) { bv = val; bi = k; }
        }
        rv[threadIdx.x]  = bv;
        rix[threadIdx.x] = bi;
        __syncthreads();
        for (int s = 128; s; s >>= 1) {
            if (threadIdx.x < s) {
                double v2 = rv[threadIdx.x + s];
                int    i2 = rix[threadIdx.x + s];
                if (v2 > rv[threadIdx.x] ||
                    (v2 == rv[threadIdx.x] && i2 < rix[threadIdx.x])) {
                    rv[threadIdx.x] = v2;
                    rix[threadIdx.x] = i2;
                }
            }
            __syncthreads();
        }
        if (threadIdx.x == 0) {
            s_new = rix[0];
            if (s_new != s_old) {
                fidx[token] = s_new;
                out[OUT_IDX + token] = (float)s_new;
                atomicAdd(&counts[s_old], -1);
                atomicAdd(&counts[s_new], 1);
            }
        }
        __syncthreads();
        if (s_new != s_old && threadIdx.x < 64) {
            int lane = threadIdx.x;
            float4 en = *(const float4*)&embed[(size_t)s_new * DIM + lane * 4];
            float4 eo = *(const float4*)&embed[(size_t)s_old * DIM + lane * 4];
            float4 zz = *(const float4*)&z[(size_t)token * DIM + lane * 4];
            float4 rn, ro, o;
            rn.x = en.x - zz.x; rn.y = en.y - zz.y; rn.z = en.z - zz.z; rn.w = en.w - zz.w;
            ro.x = eo.x - zz.x; ro.y = eo.y - zz.y; ro.z = eo.z - zz.z; ro.w = eo.w - zz.w;
            o.x = zz.x + rn.x; o.y = zz.y + rn.y; o.z = zz.z + rn.z; o.w = zz.w + rn.w;
            *(float4*)&out[(size_t)token * DIM + lane * 4] = o;
            double d = (double)rn.x * rn.x + (double)rn.y * rn.y +
                       (double)rn.z * rn.z + (double)rn.w * rn.w -
                       ((double)ro.x * ro.x + (double)ro.y * ro.y +
                        (double)ro.z * ro.z + (double)ro.w * ro.w);
            #pragma unroll
            for (int off = 32; off; off >>= 1) d += __shfl_down(d, off);
            if (lane == 0) atomicAdd(lossFix, d);
        }
    }
}

// ---------------------------------------------------------------- Phase D ---
// 1 block: sum the 1024 block partials + lossFix -> loss; entropy -> perp.
__global__ void vq_finalize(const int* __restrict__ counts,
                            const double* __restrict__ partials,
                            const double* __restrict__ lossFix,
                            float* __restrict__ out) {
    __shared__ double sh[256];
    __shared__ double sl[256];
    double s = 0.0, ls = 0.0;
    for (int b = threadIdx.x; b < K_CODE; b += 256) {
        double p = (double)counts[b] / (double)N_TOK;
        s += p * log(p + 1e-10);   // p==0 contributes exactly 0
        ls += partials[b];         // 1024 partials, same stride
    }
    sh[threadIdx.x] = s;
    sl[threadIdx.x] = ls;
    __syncthreads();
    for (int st = 128; st; st >>= 1) {
        if (threadIdx.x < st) {
            sh[threadIdx.x] += sh[threadIdx.x + st];
            sl[threadIdx.x] += sl[threadIdx.x + st];
        }
        __syncthreads();
    }
    if (threadIdx.x == 0) {
        out[OUT_PERP] = (float)exp(-sh[0]);
        out[OUT_LOSS] = (float)(1.25 * (sl[0] + *lossFix) / (double)(N_TOK) / (double)(DIM));
    }
}

// ----------------------------------------------------------------- launch ---
extern "C" void kernel_launch(void* const* d_in, const int* in_sizes, int n_in,
                              void* d_out, int out_size, void* d_ws, size_t ws_size,
                              hipStream_t stream) {
    const float* z     = (const float*)d_in[0];
    const float* embed = (const float*)d_in[1];
    float* out = (float*)d_out;
    char*  ws  = (char*)d_ws;

    int*            counts  = (int*)   (ws + WS_COUNTS);
    double*         lossFix = (double*)(ws + WS_LOSSFIX);
    int*            rcount  = (int*)   (ws + WS_RCOUNT);
    double*         parts   = (double*)(ws + WS_PART);
    int*            fidx    = (int*)   (ws + WS_FIDX);
    int*            rlist   = (int*)   (ws + WS_RLIST);
    unsigned short* bext    = (unsigned short*)(ws + WS_BEXT);

    vq_pack    <<<256,  256, 0, stream>>>(embed, bext, (int*)ws);
    vq_argmax  <<<N_TOK / 128, 256, 0, stream>>>(z, bext, embed, fidx, rcount, rlist,
                                                 out, counts, parts);
    vq_recheck <<<512,  256, 0, stream>>>(z, embed, rcount, rlist, fidx, out, counts, lossFix);
    vq_finalize<<<1,    256, 0, stream>>>(counts, parts, lossFix, out);
}